// Round 5
// baseline (12016.228 us; speedup 1.0000x reference)
//
#include <hip/hip_runtime.h>

#define Bsz  4
#define Lsz  4096
#define Csz  1024
#define NHsz 16
#define CSsz 16
#define HFsz 64
#define HF4sz 256
#define NCsz 256

// ---------------------------------------------------------------------------
// fp32 GEMM: C[M,N] = A[M,K] @ B[K,N].  64x64 tile, BK=16, 4x4 microtile.
// (unchanged)
// ---------------------------------------------------------------------------
__global__ __launch_bounds__(256)
void gemm64(const float* __restrict__ A, const float* __restrict__ Bm,
            float* __restrict__ Cm, int M, int N, int K)
{
  __shared__ __attribute__((aligned(16))) float As[16][68];
  __shared__ __attribute__((aligned(16))) float Bs[16][64];
  const int t  = threadIdx.x;
  const int tx = t & 15, ty = t >> 4;
  const int row0 = blockIdx.y * 64, col0 = blockIdx.x * 64;
  const int ar = t >> 2, ak = (t & 3) * 4;
  const int bk = t >> 4, bc = (t & 15) * 4;
  float acc[4][4] = {};

  for (int k0 = 0; k0 < K; k0 += 16) {
    float4 a4 = *(const float4*)&A[(size_t)(row0 + ar) * K + k0 + ak];
    float4 b4 = *(const float4*)&Bm[(size_t)(k0 + bk) * N + col0 + bc];
    As[ak + 0][ar] = a4.x; As[ak + 1][ar] = a4.y;
    As[ak + 2][ar] = a4.z; As[ak + 3][ar] = a4.w;
    *(float4*)&Bs[bk][bc] = b4;
    __syncthreads();
#pragma unroll
    for (int kk = 0; kk < 16; ++kk) {
      float4 av = *(const float4*)&As[kk][ty * 4];
      float4 bv = *(const float4*)&Bs[kk][tx * 4];
      acc[0][0] += av.x * bv.x; acc[0][1] += av.x * bv.y;
      acc[0][2] += av.x * bv.z; acc[0][3] += av.x * bv.w;
      acc[1][0] += av.y * bv.x; acc[1][1] += av.y * bv.y;
      acc[1][2] += av.y * bv.z; acc[1][3] += av.y * bv.w;
      acc[2][0] += av.z * bv.x; acc[2][1] += av.z * bv.y;
      acc[2][2] += av.z * bv.z; acc[2][3] += av.z * bv.w;
      acc[3][0] += av.w * bv.x; acc[3][1] += av.w * bv.y;
      acc[3][2] += av.w * bv.z; acc[3][3] += av.w * bv.w;
    }
    __syncthreads();
  }
#pragma unroll
  for (int r = 0; r < 4; ++r) {
    float4 v = make_float4(acc[r][0], acc[r][1], acc[r][2], acc[r][3]);
    *(float4*)&Cm[(size_t)(row0 + ty * 4 + r) * N + col0 + tx * 4] = v;
  }
}

// ---------------------------------------------------------------------------
// ilr -> coeff table (unchanged)
// ---------------------------------------------------------------------------
__global__ __launch_bounds__(256)
void ilr_coeff(const float* __restrict__ H, const float* __restrict__ Wil,
               const float* __restrict__ bil, float* __restrict__ coeff)
{
  __shared__ float sRow[4][1024];
  __shared__ float sP[4][16][17];
  const int t = threadIdx.x;
  const size_t r0 = (size_t)blockIdx.x * 4;
  for (int rr = 0; rr < 4; ++rr)
    for (int c = t; c < 1024; c += 256)
      sRow[rr][c] = H[(r0 + rr) * 1024 + c];
  __syncthreads();
  const int hh = t & 15, sl = t >> 4;
  for (int rr = 0; rr < 4; ++rr) {
    float acc = 0.f;
    for (int kk = 0; kk < 64; ++kk)
      acc += sRow[rr][sl * 64 + kk] * Wil[(sl * 64 + kk) * 16 + hh];
    sP[rr][sl][hh] = acc;
  }
  __syncthreads();
  if (t < 64) {
    const int rr = t >> 4, h2 = t & 15;
    float s = 0.f;
    for (int sl2 = 0; sl2 < 16; ++sl2) s += sP[rr][sl2][h2];
    s += bil[h2];
    const float sig = 1.f / (1.f + expf(-s));
    const int r  = (int)(r0 + rr);
    const int b  = r >> 12, l = r & 4095, nc = l >> 4, cs = l & 15;
    coeff[((b * 16 + h2) * NCsz + nc) * CSsz + cs] = sig / ((float)(cs + 1) * 64.0f);
  }
}

// ---------------------------------------------------------------------------
// TTT scan v6: 1024 threads = 16 waves = 4 waves/SIMD (2A+2B per SIMD).
//
// Round-4 post-mortem: LDS-pipe theory dead (40% fewer DS instr -> -3.5%).
// Real limiter: per-phase critical path with only 1 active wave/SIMD during
// specialized phases (8 waves, 1A+1B per SIMD, one idles at the barrier) ->
// in-order stream with exposed LDS/L2 latency.  v6 doubles waves and halves
// per-wave work so every phase has >=2 active waves/SIMD:
//   A' (t<512):  thread (n, h2) owns FULL W1 column n (64 regs, duplicated
//                across h2) but computes only rows i in [h2*8, h2*8+8).
//                W1 update applies all 16 i to both copies (consistent).
//   B' (t>=512): w2r = W2[n][h2*32..+32) (32 regs, row half; g1 +row-update
//                split by mm-half, partials combined on read).
//                w2c = W2[qq*32..+32)[m] (32 regs; Z2/Z2b partials over 8
//                qq-slices, reduced in P3/P7).
// LDS 104KB -> 1 WG/CU -> 4 waves/EU -> 128-VGPR budget (A~90/B~100 peak,
// no spill).  6 barriers/chunk.
// ---------------------------------------------------------------------------
__global__ __launch_bounds__(1024)
void ttt_scan(const float* __restrict__ XA, const float* __restrict__ XBuf,
              const float* __restrict__ XCbuf, const float* __restrict__ coeff,
              const float* __restrict__ W1g, const float* __restrict__ W2g,
              float* __restrict__ Out)
{
  __shared__ __attribute__((aligned(16))) float sZ1[16 * 260];    // 16.6 KB
  __shared__ __attribute__((aligned(16))) float sZ1b[16 * 260];   // 16.6 KB
  __shared__ __attribute__((aligned(16))) float sg2[16 * 68];     //  4.3 KB
  __shared__ __attribute__((aligned(16))) float sP[8 * 16 * 64];  // 32 KB: Z2/Z2b partials [qq][i][m]
  __shared__ __attribute__((aligned(16))) float sPg[2 * 16 * 256];// 32 KB: g1 partials [hB][i][n]
  __shared__ float sA1[16 * 17];
  __shared__ float sA2p[2 * 16 * 17];
  __shared__ float sCoBuf[2 * 16];
  // total ~104 KB -> only 1 WG/CU fits (matches grid: 64 blocks on 256 CUs)

  const int t  = threadIdx.x;
  const int bh = blockIdx.x;              // 0..63
  const int b  = bh >> 4, h = bh & 15;
  const bool isA = (t < 512);
  const int n  = t & 255;                 // A: W1 col / B: W2 row
  const int h2 = (t >> 8) & 1;            // A: i-half ; B: mm-half (w2r)
  const int m  = t & 63;                  // B: W2 col (w2c)
  const int qq = (t >> 6) & 7;            // B: kk-slice (w2c)

  // Overlaid persistent state: A: w1 col = wreg[0:64].
  //                            B: w2r = wreg[0:32], w2c = wreg[32:64].
  float wreg[64];
  float zb[8];                            // A: z1bp rows (P2 -> P5)
#define W1R(k)  wreg[(k)]
#define W2RR(j) wreg[(j)]
#define W2CR(j) wreg[32 + (j)]

  float xa;                               // XA prefetch (all threads, 1 elem)

  const float* W1h = W1g + h * HFsz * HF4sz;
  const float* W2h = W2g + h * HF4sz * HFsz;
  if (isA) {
#pragma unroll
    for (int k = 0; k < 64; ++k) W1R(k) = W1h[k * 256 + n];
  } else {
#pragma unroll
    for (int j = 0; j < 32; ++j) W2RR(j) = W2h[n * 64 + h2 * 32 + j];
#pragma unroll
    for (int j = 0; j < 32; ++j) W2CR(j) = W2h[(qq * 32 + j) * 64 + m];
  }

  // ---- pre-loop: coeff chunk 0 + XA prefetch ----------------------------
  {
    const int cb0 = (b * Lsz) * Csz + h * HFsz;
    if (t < 16) sCoBuf[t] = coeff[(bh * NCsz + 0) * CSsz + t];
    xa = XA[cb0 + (t >> 6) * 1024 + (t & 63)];
  }
  __syncthreads();

#pragma unroll 1
  for (int nc = 0; nc < NCsz; ++nc) {
    const int cur = nc & 1, nxt = cur ^ 1;
    const int cb  = (b * Lsz + nc * CSsz) * Csz + h * HFsz;
    const int nc1 = (nc + 1) & (NCsz - 1);
    const int cb1 = (b * Lsz + nc1 * CSsz) * Csz + h * HFsz;
    const float* __restrict__ xbG = XBuf  + cb;   // 16 rows, stride 1024
    const float* __restrict__ xcG = XCbuf + cb;

    const float cl = sCoBuf[cur * 16 + 15];
    float conext = 0.f;
    if (t < 16) conext = coeff[(bh * NCsz + nc1) * CSsz + t];

    // ---- P1: A: Z1 rows [h2*8,+8) = XB@W1 (full K, uniform loads) -> sZ1
    //          B(first 256): Attn1 = tril(XC@XB^T) -> sA1 (zero-filled) ----
    if (isA) {
      const float* __restrict__ xb8 = xbG + (h2 << 13);  // rows h2*8..
      float acc[8];
#pragma unroll
      for (int r = 0; r < 8; ++r) acc[r] = 0.f;
#pragma unroll
      for (int k = 0; k < 64; k += 4) {
        const float wa = W1R(k), wb = W1R(k + 1), wc = W1R(k + 2), wd = W1R(k + 3);
#pragma unroll
        for (int r = 0; r < 8; ++r) {
          const float4 x = *(const float4*)&xb8[r * 1024 + k];
          acc[r] = fmaf(x.w, wd, fmaf(x.z, wc, fmaf(x.y, wb, fmaf(x.x, wa, acc[r]))));
        }
      }
      const int ib = h2 * 8;
#pragma unroll
      for (int r = 0; r < 8; ++r) sZ1[(ib + r) * 260 + n] = acc[r];
    } else if ((t & 511) < 256) {
      const int ia = (t >> 4) & 15, ja = t & 15;
      float a0 = 0.f, a1 = 0.f;
      if (ja <= ia) {
#pragma unroll
        for (int k = 0; k < 64; k += 8) {
          const float4 c0 = *(const float4*)&xcG[ia * 1024 + k];
          const float4 b0 = *(const float4*)&xbG[ja * 1024 + k];
          const float4 c1 = *(const float4*)&xcG[ia * 1024 + k + 4];
          const float4 b1 = *(const float4*)&xbG[ja * 1024 + k + 4];
          a0 = fmaf(c0.w, b0.w, fmaf(c0.z, b0.z, fmaf(c0.y, b0.y, fmaf(c0.x, b0.x, a0))));
          a1 = fmaf(c1.w, b1.w, fmaf(c1.z, b1.z, fmaf(c1.y, b1.y, fmaf(c1.x, b1.x, a1))));
        }
      }
      sA1[ia * 17 + ja] = a0 + a1;   // 0 for upper triangle
    }
    __syncthreads();

    // ---- P2: A: z1bp rows [h2*8,+8) = XC@W1 -> zb regs
    //          B: Z2 partials (kk-slice qq) -> sP ------------------------
    if (isA) {
      const float* __restrict__ xc8 = xcG + (h2 << 13);
#pragma unroll
      for (int r = 0; r < 8; ++r) zb[r] = 0.f;
#pragma unroll
      for (int k = 0; k < 64; k += 4) {
        const float wa = W1R(k), wb = W1R(k + 1), wc = W1R(k + 2), wd = W1R(k + 3);
#pragma unroll
        for (int r = 0; r < 8; ++r) {
          const float4 x = *(const float4*)&xc8[r * 1024 + k];
          zb[r] = fmaf(x.w, wd, fmaf(x.z, wc, fmaf(x.y, wb, fmaf(x.x, wa, zb[r]))));
        }
      }
    } else {
      const int ko = qq << 5;
      float acc[16];
#pragma unroll
      for (int i = 0; i < 16; ++i) acc[i] = 0.f;
#pragma unroll
      for (int kk = 0; kk < 32; kk += 4) {
        const float wa = W2CR(kk), wb = W2CR(kk + 1), wc = W2CR(kk + 2), wd = W2CR(kk + 3);
#pragma unroll
        for (int i = 0; i < 16; ++i) {
          const float4 z = *(const float4*)&sZ1[i * 260 + ko + kk];
          acc[i] = fmaf(z.w, wd, fmaf(z.z, wc, fmaf(z.y, wb, fmaf(z.x, wa, acc[i]))));
        }
      }
#pragma unroll
      for (int i = 0; i < 16; ++i) sP[(qq << 10) + (i << 6) + m] = acc[i];
    }
    __syncthreads();

    // ---- P3: all 1024: g2[i][m] = sum_qq Z2p - XA -> sg2 ; coeff stage --
    {
      const int i3 = t >> 6, m3 = t & 63;
      float v = 0.f;
#pragma unroll
      for (int p = 0; p < 8; ++p) v += sP[(p << 10) + (i3 << 6) + m3];
      v -= xa;
      sg2[i3 * 68 + m3] = v;
      xa = XA[cb1 + i3 * 1024 + m3];        // prefetch next chunk
      if (t < 16) sCoBuf[nxt * 16 + t] = conext;
    }
    __syncthreads();

    // ---- P4: B: g1 partials (mm-half h2) -> sPg + w2r half-row update ---
    if (!isA) {
      const int mb = h2 << 5;
      float s[16];
#pragma unroll
      for (int i = 0; i < 16; ++i) s[i] = cl * sZ1[i * 260 + n];
      float acc[16];
#pragma unroll
      for (int i = 0; i < 16; ++i) acc[i] = 0.f;
#pragma unroll
      for (int mm = 0; mm < 32; mm += 4) {
        const float wa = W2RR(mm), wb = W2RR(mm + 1), wc = W2RR(mm + 2), wd = W2RR(mm + 3);
        float d0 = 0.f, d1 = 0.f, d2 = 0.f, d3 = 0.f;
#pragma unroll
        for (int i = 0; i < 16; ++i) {
          const float4 g = *(const float4*)&sg2[i * 68 + mb + mm];
          acc[i] = fmaf(g.w, wd, fmaf(g.z, wc, fmaf(g.y, wb, fmaf(g.x, wa, acc[i]))));
          d0 = fmaf(s[i], g.x, d0); d1 = fmaf(s[i], g.y, d1);
          d2 = fmaf(s[i], g.z, d2); d3 = fmaf(s[i], g.w, d3);
        }
        W2RR(mm + 0) -= d0; W2RR(mm + 1) -= d1;
        W2RR(mm + 2) -= d2; W2RR(mm + 3) -= d3;
      }
#pragma unroll
      for (int i = 0; i < 16; ++i) sPg[(h2 << 12) + (i << 8) + n] = acc[i];
    }
    __syncthreads();

    // ---- P5: A: Z1b rows [h2*8,+8) finalize -> sZ1b ---------------------
    if (isA) {
      float g1v[16];
#pragma unroll
      for (int j = 0; j < 16; ++j)
        g1v[j] = sPg[(j << 8) + n] + sPg[4096 + (j << 8) + n];
      const int ib = h2 * 8;
#pragma unroll
      for (int r = 0; r < 8; ++r) {
        const int i = ib + r;
        float at = 0.f;
#pragma unroll
        for (int j = 0; j < 16; ++j) at = fmaf(sA1[i * 17 + j], g1v[j], at);
        const float z = fmaf(-sCoBuf[cur * 16 + i], at, zb[r]);
        sZ1b[i * 260 + n] = z;
      }
    }
    __syncthreads();

    // ---- P6: A: Attn2 K-half -> sA2p, W1 full update (uniform XB loads)
    //          B: Z2b partials -> sP, w2c slice update --------------------
    if (isA) {
      const int ia = n >> 4, ja = n & 15;
      const int kb = h2 << 7;     // K-half offset (floats)
      float a0 = 0.f, a1 = 0.f, a2 = 0.f, a3 = 0.f;
      if (ja <= ia) {
#pragma unroll
        for (int kk = 0; kk < 128; kk += 16) {
          const float4 p0 = *(const float4*)&sZ1b[ia * 260 + kb + kk];
          const float4 z0 = *(const float4*)&sZ1 [ja * 260 + kb + kk];
          const float4 p1 = *(const float4*)&sZ1b[ia * 260 + kb + kk + 4];
          const float4 z1 = *(const float4*)&sZ1 [ja * 260 + kb + kk + 4];
          const float4 p2 = *(const float4*)&sZ1b[ia * 260 + kb + kk + 8];
          const float4 z2 = *(const float4*)&sZ1 [ja * 260 + kb + kk + 8];
          const float4 p3 = *(const float4*)&sZ1b[ia * 260 + kb + kk + 12];
          const float4 z3 = *(const float4*)&sZ1 [ja * 260 + kb + kk + 12];
          a0 = fmaf(p0.w, z0.w, fmaf(p0.z, z0.z, fmaf(p0.y, z0.y, fmaf(p0.x, z0.x, a0))));
          a1 = fmaf(p1.w, z1.w, fmaf(p1.z, z1.z, fmaf(p1.y, z1.y, fmaf(p1.x, z1.x, a1))));
          a2 = fmaf(p2.w, z2.w, fmaf(p2.z, z2.z, fmaf(p2.y, z2.y, fmaf(p2.x, z2.x, a2))));
          a3 = fmaf(p3.w, z3.w, fmaf(p3.z, z3.z, fmaf(p3.y, z3.y, fmaf(p3.x, z3.x, a3))));
        }
      }
      sA2p[h2 * 272 + ia * 17 + ja] = (a0 + a1) + (a2 + a3);
      // W1 update: both copies apply ALL 16 i (keeps duplicates coherent)
      float g1u[16];
#pragma unroll
      for (int j = 0; j < 16; ++j)
        g1u[j] = cl * (sPg[(j << 8) + n] + sPg[4096 + (j << 8) + n]);
#pragma unroll
      for (int i = 0; i < 16; ++i) {
#pragma unroll
        for (int k = 0; k < 64; k += 4) {
          const float4 x = *(const float4*)&xbG[i * 1024 + k];
          W1R(k + 0) -= g1u[i] * x.x; W1R(k + 1) -= g1u[i] * x.y;
          W1R(k + 2) -= g1u[i] * x.z; W1R(k + 3) -= g1u[i] * x.w;
        }
      }
    } else {
      const int ko = qq << 5;
      float acc[16];
#pragma unroll
      for (int i = 0; i < 16; ++i) acc[i] = 0.f;
#pragma unroll
      for (int kk = 0; kk < 32; kk += 4) {
        const float wa = W2CR(kk), wb = W2CR(kk + 1), wc = W2CR(kk + 2), wd = W2CR(kk + 3);
#pragma unroll
        for (int i = 0; i < 16; ++i) {
          const float4 z = *(const float4*)&sZ1b[i * 260 + ko + kk];
          acc[i] = fmaf(z.w, wd, fmaf(z.z, wc, fmaf(z.y, wb, fmaf(z.x, wa, acc[i]))));
        }
      }
#pragma unroll
      for (int i = 0; i < 16; ++i) sP[(qq << 10) + (i << 6) + m] = acc[i];
      // w2c slice update (pre-update Z1 from sZ1, g2 from sg2)
      float s2[16];
#pragma unroll
      for (int i = 0; i < 16; ++i) s2[i] = cl * sg2[i * 68 + m];
#pragma unroll
      for (int kk = 0; kk < 32; kk += 4) {
        float d0 = 0.f, d1 = 0.f, d2 = 0.f, d3 = 0.f;
#pragma unroll
        for (int i = 0; i < 16; ++i) {
          const float4 z = *(const float4*)&sZ1[i * 260 + ko + kk];
          d0 = fmaf(s2[i], z.x, d0); d1 = fmaf(s2[i], z.y, d1);
          d2 = fmaf(s2[i], z.z, d2); d3 = fmaf(s2[i], z.w, d3);
        }
        W2CR(kk + 0) -= d0; W2CR(kk + 1) -= d1;
        W2CR(kk + 2) -= d2; W2CR(kk + 3) -= d3;
      }
    }
    __syncthreads();

    // ---- P7: A: Z2b reduce + Attn2 combine + store (2 outputs/thread).
    //      No trailing barrier: B proceeds into next P1 (writes only sA1,
    //      not read here); next writes to sP/sA2p/sg2 are >=2 barriers away.
    if (isA) {
      const int mm = n & 63, iq = (n >> 6) & 3;
#pragma unroll
      for (int r = 0; r < 2; ++r) {
        const int i = iq + 4 * (h2 * 2 + r);
        float v = 0.f;
#pragma unroll
        for (int p = 0; p < 8; ++p) v += sP[(p << 10) + (i << 6) + mm];
        float at = 0.f;
#pragma unroll
        for (int j = 0; j < 16; ++j)
          at = fmaf(sA2p[i * 17 + j] + sA2p[272 + i * 17 + j],
                    sg2[j * 68 + mm], at);
        Out[cb + i * 1024 + mm] = v - sCoBuf[cur * 16 + i] * at;
      }
    }
  }
#undef W1R
#undef W2RR
#undef W2CR
}

// ---------------------------------------------------------------------------
// Workspace (fp32 floats): bXC [0,16.7M) | bXB [16.7M,33.5M) | bZ2b
// [33.5M,50.3M) | bCo [50.3M,+262k).  193 MiB total.  XA (V proj) lives in
// d_out until the final GEMM overwrites it (stream-ordered, safe).
// ---------------------------------------------------------------------------
extern "C" void kernel_launch(void* const* d_in, const int* in_sizes, int n_in,
                              void* d_out, int out_size, void* d_ws, size_t ws_size,
                              hipStream_t stream)
{
  const float* H    = (const float*)d_in[0];
  const float* Wq   = (const float*)d_in[1];
  const float* Wk   = (const float*)d_in[2];
  const float* Wv   = (const float*)d_in[3];
  const float* Wo   = (const float*)d_in[4];
  const float* Wil  = (const float*)d_in[5];
  const float* bil  = (const float*)d_in[6];
  const float* W1   = (const float*)d_in[7];
  const float* W2   = (const float*)d_in[8];
  float* out        = (float*)d_out;

  float* ws    = (float*)d_ws;
  float* bXC   = ws;
  float* bXB   = ws + 16777216;
  float* bZ2b  = ws + 33554432;
  float* bCo   = ws + 50331648;
  float* bXA   = out;

  const int M = Bsz * Lsz, N = Csz, K = Csz;
  dim3 gg(N / 64, M / 64);
  dim3 bb(256);

  gemm64<<<gg, bb, 0, stream>>>(H, Wq, bXC, M, N, K);
  gemm64<<<gg, bb, 0, stream>>>(H, Wk, bXB, M, N, K);
  gemm64<<<gg, bb, 0, stream>>>(H, Wv, bXA, M, N, K);
  ilr_coeff<<<M / 4, 256, 0, stream>>>(H, Wil, bil, bCo);
  ttt_scan<<<Bsz * NHsz, 1024, 0, stream>>>(bXA, bXB, bXC, bCo, W1, W2, bZ2b);
  gemm64<<<gg, bb, 0, stream>>>(bZ2b, Wo, out, M, N, K);
}

// Round 6
// 12006.457 us; speedup vs baseline: 1.0008x; 1.0008x over previous
//
#include <hip/hip_runtime.h>

#define Bsz  4
#define Lsz  4096
#define Csz  1024
#define NHsz 16
#define CSsz 16
#define HFsz 64
#define HF4sz 256
#define NCsz 256

// ---------------------------------------------------------------------------
// fp32 GEMM: C[M,N] = A[M,K] @ B[K,N].  64x64 tile, BK=16, 4x4 microtile.
// (unchanged)
// ---------------------------------------------------------------------------
__global__ __launch_bounds__(256)
void gemm64(const float* __restrict__ A, const float* __restrict__ Bm,
            float* __restrict__ Cm, int M, int N, int K)
{
  __shared__ __attribute__((aligned(16))) float As[16][68];
  __shared__ __attribute__((aligned(16))) float Bs[16][64];
  const int t  = threadIdx.x;
  const int tx = t & 15, ty = t >> 4;
  const int row0 = blockIdx.y * 64, col0 = blockIdx.x * 64;
  const int ar = t >> 2, ak = (t & 3) * 4;
  const int bk = t >> 4, bc = (t & 15) * 4;
  float acc[4][4] = {};

  for (int k0 = 0; k0 < K; k0 += 16) {
    float4 a4 = *(const float4*)&A[(size_t)(row0 + ar) * K + k0 + ak];
    float4 b4 = *(const float4*)&Bm[(size_t)(k0 + bk) * N + col0 + bc];
    As[ak + 0][ar] = a4.x; As[ak + 1][ar] = a4.y;
    As[ak + 2][ar] = a4.z; As[ak + 3][ar] = a4.w;
    *(float4*)&Bs[bk][bc] = b4;
    __syncthreads();
#pragma unroll
    for (int kk = 0; kk < 16; ++kk) {
      float4 av = *(const float4*)&As[kk][ty * 4];
      float4 bv = *(const float4*)&Bs[kk][tx * 4];
      acc[0][0] += av.x * bv.x; acc[0][1] += av.x * bv.y;
      acc[0][2] += av.x * bv.z; acc[0][3] += av.x * bv.w;
      acc[1][0] += av.y * bv.x; acc[1][1] += av.y * bv.y;
      acc[1][2] += av.y * bv.z; acc[1][3] += av.y * bv.w;
      acc[2][0] += av.z * bv.x; acc[2][1] += av.z * bv.y;
      acc[2][2] += av.z * bv.z; acc[2][3] += av.z * bv.w;
      acc[3][0] += av.w * bv.x; acc[3][1] += av.w * bv.y;
      acc[3][2] += av.w * bv.z; acc[3][3] += av.w * bv.w;
    }
    __syncthreads();
  }
#pragma unroll
  for (int r = 0; r < 4; ++r) {
    float4 v = make_float4(acc[r][0], acc[r][1], acc[r][2], acc[r][3]);
    *(float4*)&Cm[(size_t)(row0 + ty * 4 + r) * N + col0 + tx * 4] = v;
  }
}

// ---------------------------------------------------------------------------
// ilr -> coeff table (unchanged)
// ---------------------------------------------------------------------------
__global__ __launch_bounds__(256)
void ilr_coeff(const float* __restrict__ H, const float* __restrict__ Wil,
               const float* __restrict__ bil, float* __restrict__ coeff)
{
  __shared__ float sRow[4][1024];
  __shared__ float sP[4][16][17];
  const int t = threadIdx.x;
  const size_t r0 = (size_t)blockIdx.x * 4;
  for (int rr = 0; rr < 4; ++rr)
    for (int c = t; c < 1024; c += 256)
      sRow[rr][c] = H[(r0 + rr) * 1024 + c];
  __syncthreads();
  const int hh = t & 15, sl = t >> 4;
  for (int rr = 0; rr < 4; ++rr) {
    float acc = 0.f;
    for (int kk = 0; kk < 64; ++kk)
      acc += sRow[rr][sl * 64 + kk] * Wil[(sl * 64 + kk) * 16 + hh];
    sP[rr][sl][hh] = acc;
  }
  __syncthreads();
  if (t < 64) {
    const int rr = t >> 4, h2 = t & 15;
    float s = 0.f;
    for (int sl2 = 0; sl2 < 16; ++sl2) s += sP[rr][sl2][h2];
    s += bil[h2];
    const float sig = 1.f / (1.f + expf(-s));
    const int r  = (int)(r0 + rr);
    const int b  = r >> 12, l = r & 4095, nc = l >> 4, cs = l & 15;
    coeff[((b * 16 + h2) * NCsz + nc) * CSsz + cs] = sig / ((float)(cs + 1) * 64.0f);
  }
}

// ---------------------------------------------------------------------------
// TTT scan v7: v6 structure (1024 thr, 16 waves, 2A+2B per SIMD) with the
// register budget finally fixed.
//
// Round-5 post-mortem: v6's VGPR came back 64 (not 128): the backend targets
// 2 workgroups/CU regardless of LDS/grid (512thr->128, 1024thr->64), and the
// bare amdgpu_waves_per_eu attribute is ignored.  ~100 live regs vs 64 cap ->
// ~40 spilled -> WRITE_SIZE 233MB.  Yet occupancy doubled (12.3%) and
// VALUBusy ROSE to 11.4% while dur only slipped 9% against 170MB of spill
// traffic -> TLP structure is right, spills are the tax.
//
// v7: __launch_bounds__(1024, 4) -- documented 2nd arg = min waves/EU = 4
// -> per-wave VGPR cap 512/4 = 128 >= ~100 needed -> no spill.
// ---------------------------------------------------------------------------
__global__ __launch_bounds__(1024, 4)
void ttt_scan(const float* __restrict__ XA, const float* __restrict__ XBuf,
              const float* __restrict__ XCbuf, const float* __restrict__ coeff,
              const float* __restrict__ W1g, const float* __restrict__ W2g,
              float* __restrict__ Out)
{
  __shared__ __attribute__((aligned(16))) float sZ1[16 * 260];    // 16.6 KB
  __shared__ __attribute__((aligned(16))) float sZ1b[16 * 260];   // 16.6 KB
  __shared__ __attribute__((aligned(16))) float sg2[16 * 68];     //  4.3 KB
  __shared__ __attribute__((aligned(16))) float sP[8 * 16 * 64];  // 32 KB: Z2/Z2b partials [qq][i][m]
  __shared__ __attribute__((aligned(16))) float sPg[2 * 16 * 256];// 32 KB: g1 partials [hB][i][n]
  __shared__ float sA1[16 * 17];
  __shared__ float sA2p[2 * 16 * 17];
  __shared__ float sCoBuf[2 * 16];
  // total ~104 KB -> 1 WG/CU (matches grid: 64 blocks on 256 CUs)

  const int t  = threadIdx.x;
  const int bh = blockIdx.x;              // 0..63
  const int b  = bh >> 4, h = bh & 15;
  const bool isA = (t < 512);
  const int n  = t & 255;                 // A: W1 col / B: W2 row
  const int h2 = (t >> 8) & 1;            // A: i-half ; B: mm-half (w2r)
  const int m  = t & 63;                  // B: W2 col (w2c)
  const int qq = (t >> 6) & 7;            // B: kk-slice (w2c)

  // Overlaid persistent state: A: w1 col = wreg[0:64].
  //                            B: w2r = wreg[0:32], w2c = wreg[32:64].
  float wreg[64];
  float zb[8];                            // A: z1bp rows (P2 -> P5)
#define W1R(k)  wreg[(k)]
#define W2RR(j) wreg[(j)]
#define W2CR(j) wreg[32 + (j)]

  float xa;                               // XA prefetch (all threads, 1 elem)

  const float* W1h = W1g + h * HFsz * HF4sz;
  const float* W2h = W2g + h * HF4sz * HFsz;
  if (isA) {
#pragma unroll
    for (int k = 0; k < 64; ++k) W1R(k) = W1h[k * 256 + n];
  } else {
#pragma unroll
    for (int j = 0; j < 32; ++j) W2RR(j) = W2h[n * 64 + h2 * 32 + j];
#pragma unroll
    for (int j = 0; j < 32; ++j) W2CR(j) = W2h[(qq * 32 + j) * 64 + m];
  }

  // ---- pre-loop: coeff chunk 0 + XA prefetch ----------------------------
  {
    const int cb0 = (b * Lsz) * Csz + h * HFsz;
    if (t < 16) sCoBuf[t] = coeff[(bh * NCsz + 0) * CSsz + t];
    xa = XA[cb0 + (t >> 6) * 1024 + (t & 63)];
  }
  __syncthreads();

#pragma unroll 1
  for (int nc = 0; nc < NCsz; ++nc) {
    const int cur = nc & 1, nxt = cur ^ 1;
    const int cb  = (b * Lsz + nc * CSsz) * Csz + h * HFsz;
    const int nc1 = (nc + 1) & (NCsz - 1);
    const int cb1 = (b * Lsz + nc1 * CSsz) * Csz + h * HFsz;
    const float* __restrict__ xbG = XBuf  + cb;   // 16 rows, stride 1024
    const float* __restrict__ xcG = XCbuf + cb;

    const float cl = sCoBuf[cur * 16 + 15];
    float conext = 0.f;
    if (t < 16) conext = coeff[(bh * NCsz + nc1) * CSsz + t];

    // ---- P1: A: Z1 rows [h2*8,+8) = XB@W1 (full K, uniform loads) -> sZ1
    //          B(first 256): Attn1 = tril(XC@XB^T) -> sA1 (zero-filled) ----
    if (isA) {
      const float* __restrict__ xb8 = xbG + (h2 << 13);  // rows h2*8..
      float acc[8];
#pragma unroll
      for (int r = 0; r < 8; ++r) acc[r] = 0.f;
#pragma unroll
      for (int k = 0; k < 64; k += 4) {
        const float wa = W1R(k), wb = W1R(k + 1), wc = W1R(k + 2), wd = W1R(k + 3);
#pragma unroll
        for (int r = 0; r < 8; ++r) {
          const float4 x = *(const float4*)&xb8[r * 1024 + k];
          acc[r] = fmaf(x.w, wd, fmaf(x.z, wc, fmaf(x.y, wb, fmaf(x.x, wa, acc[r]))));
        }
      }
      const int ib = h2 * 8;
#pragma unroll
      for (int r = 0; r < 8; ++r) sZ1[(ib + r) * 260 + n] = acc[r];
    } else if ((t & 511) < 256) {
      const int ia = (t >> 4) & 15, ja = t & 15;
      float a0 = 0.f, a1 = 0.f;
      if (ja <= ia) {
#pragma unroll
        for (int k = 0; k < 64; k += 8) {
          const float4 c0 = *(const float4*)&xcG[ia * 1024 + k];
          const float4 b0 = *(const float4*)&xbG[ja * 1024 + k];
          const float4 c1 = *(const float4*)&xcG[ia * 1024 + k + 4];
          const float4 b1 = *(const float4*)&xbG[ja * 1024 + k + 4];
          a0 = fmaf(c0.w, b0.w, fmaf(c0.z, b0.z, fmaf(c0.y, b0.y, fmaf(c0.x, b0.x, a0))));
          a1 = fmaf(c1.w, b1.w, fmaf(c1.z, b1.z, fmaf(c1.y, b1.y, fmaf(c1.x, b1.x, a1))));
        }
      }
      sA1[ia * 17 + ja] = a0 + a1;   // 0 for upper triangle
    }
    __syncthreads();

    // ---- P2: A: z1bp rows [h2*8,+8) = XC@W1 -> zb regs
    //          B: Z2 partials (kk-slice qq) -> sP ------------------------
    if (isA) {
      const float* __restrict__ xc8 = xcG + (h2 << 13);
#pragma unroll
      for (int r = 0; r < 8; ++r) zb[r] = 0.f;
#pragma unroll
      for (int k = 0; k < 64; k += 4) {
        const float wa = W1R(k), wb = W1R(k + 1), wc = W1R(k + 2), wd = W1R(k + 3);
#pragma unroll
        for (int r = 0; r < 8; ++r) {
          const float4 x = *(const float4*)&xc8[r * 1024 + k];
          zb[r] = fmaf(x.w, wd, fmaf(x.z, wc, fmaf(x.y, wb, fmaf(x.x, wa, zb[r]))));
        }
      }
    } else {
      const int ko = qq << 5;
      float acc[16];
#pragma unroll
      for (int i = 0; i < 16; ++i) acc[i] = 0.f;
#pragma unroll
      for (int kk = 0; kk < 32; kk += 4) {
        const float wa = W2CR(kk), wb = W2CR(kk + 1), wc = W2CR(kk + 2), wd = W2CR(kk + 3);
#pragma unroll
        for (int i = 0; i < 16; ++i) {
          const float4 z = *(const float4*)&sZ1[i * 260 + ko + kk];
          acc[i] = fmaf(z.w, wd, fmaf(z.z, wc, fmaf(z.y, wb, fmaf(z.x, wa, acc[i]))));
        }
      }
#pragma unroll
      for (int i = 0; i < 16; ++i) sP[(qq << 10) + (i << 6) + m] = acc[i];
    }
    __syncthreads();

    // ---- P3: all 1024: g2[i][m] = sum_qq Z2p - XA -> sg2 ; coeff stage --
    {
      const int i3 = t >> 6, m3 = t & 63;
      float v = 0.f;
#pragma unroll
      for (int p = 0; p < 8; ++p) v += sP[(p << 10) + (i3 << 6) + m3];
      v -= xa;
      sg2[i3 * 68 + m3] = v;
      xa = XA[cb1 + i3 * 1024 + m3];        // prefetch next chunk
      if (t < 16) sCoBuf[nxt * 16 + t] = conext;
    }
    __syncthreads();

    // ---- P4: B: g1 partials (mm-half h2) -> sPg + w2r half-row update ---
    if (!isA) {
      const int mb = h2 << 5;
      float s[16];
#pragma unroll
      for (int i = 0; i < 16; ++i) s[i] = cl * sZ1[i * 260 + n];
      float acc[16];
#pragma unroll
      for (int i = 0; i < 16; ++i) acc[i] = 0.f;
#pragma unroll
      for (int mm = 0; mm < 32; mm += 4) {
        const float wa = W2RR(mm), wb = W2RR(mm + 1), wc = W2RR(mm + 2), wd = W2RR(mm + 3);
        float d0 = 0.f, d1 = 0.f, d2 = 0.f, d3 = 0.f;
#pragma unroll
        for (int i = 0; i < 16; ++i) {
          const float4 g = *(const float4*)&sg2[i * 68 + mb + mm];
          acc[i] = fmaf(g.w, wd, fmaf(g.z, wc, fmaf(g.y, wb, fmaf(g.x, wa, acc[i]))));
          d0 = fmaf(s[i], g.x, d0); d1 = fmaf(s[i], g.y, d1);
          d2 = fmaf(s[i], g.z, d2); d3 = fmaf(s[i], g.w, d3);
        }
        W2RR(mm + 0) -= d0; W2RR(mm + 1) -= d1;
        W2RR(mm + 2) -= d2; W2RR(mm + 3) -= d3;
      }
#pragma unroll
      for (int i = 0; i < 16; ++i) sPg[(h2 << 12) + (i << 8) + n] = acc[i];
    }
    __syncthreads();

    // ---- P5: A: Z1b rows [h2*8,+8) finalize -> sZ1b ---------------------
    if (isA) {
      float g1v[16];
#pragma unroll
      for (int j = 0; j < 16; ++j)
        g1v[j] = sPg[(j << 8) + n] + sPg[4096 + (j << 8) + n];
      const int ib = h2 * 8;
#pragma unroll
      for (int r = 0; r < 8; ++r) {
        const int i = ib + r;
        float at = 0.f;
#pragma unroll
        for (int j = 0; j < 16; ++j) at = fmaf(sA1[i * 17 + j], g1v[j], at);
        const float z = fmaf(-sCoBuf[cur * 16 + i], at, zb[r]);
        sZ1b[i * 260 + n] = z;
      }
    }
    __syncthreads();

    // ---- P6: A: Attn2 K-half -> sA2p, W1 full update (uniform XB loads)
    //          B: Z2b partials -> sP, w2c slice update --------------------
    if (isA) {
      const int ia = n >> 4, ja = n & 15;
      const int kb = h2 << 7;     // K-half offset (floats)
      float a0 = 0.f, a1 = 0.f, a2 = 0.f, a3 = 0.f;
      if (ja <= ia) {
#pragma unroll
        for (int kk = 0; kk < 128; kk += 16) {
          const float4 p0 = *(const float4*)&sZ1b[ia * 260 + kb + kk];
          const float4 z0 = *(const float4*)&sZ1 [ja * 260 + kb + kk];
          const float4 p1 = *(const float4*)&sZ1b[ia * 260 + kb + kk + 4];
          const float4 z1 = *(const float4*)&sZ1 [ja * 260 + kb + kk + 4];
          const float4 p2 = *(const float4*)&sZ1b[ia * 260 + kb + kk + 8];
          const float4 z2 = *(const float4*)&sZ1 [ja * 260 + kb + kk + 8];
          const float4 p3 = *(const float4*)&sZ1b[ia * 260 + kb + kk + 12];
          const float4 z3 = *(const float4*)&sZ1 [ja * 260 + kb + kk + 12];
          a0 = fmaf(p0.w, z0.w, fmaf(p0.z, z0.z, fmaf(p0.y, z0.y, fmaf(p0.x, z0.x, a0))));
          a1 = fmaf(p1.w, z1.w, fmaf(p1.z, z1.z, fmaf(p1.y, z1.y, fmaf(p1.x, z1.x, a1))));
          a2 = fmaf(p2.w, z2.w, fmaf(p2.z, z2.z, fmaf(p2.y, z2.y, fmaf(p2.x, z2.x, a2))));
          a3 = fmaf(p3.w, z3.w, fmaf(p3.z, z3.z, fmaf(p3.y, z3.y, fmaf(p3.x, z3.x, a3))));
        }
      }
      sA2p[h2 * 272 + ia * 17 + ja] = (a0 + a1) + (a2 + a3);
      // W1 update: both copies apply ALL 16 i (keeps duplicates coherent)
      float g1u[16];
#pragma unroll
      for (int j = 0; j < 16; ++j)
        g1u[j] = cl * (sPg[(j << 8) + n] + sPg[4096 + (j << 8) + n]);
#pragma unroll
      for (int i = 0; i < 16; ++i) {
#pragma unroll
        for (int k = 0; k < 64; k += 4) {
          const float4 x = *(const float4*)&xbG[i * 1024 + k];
          W1R(k + 0) -= g1u[i] * x.x; W1R(k + 1) -= g1u[i] * x.y;
          W1R(k + 2) -= g1u[i] * x.z; W1R(k + 3) -= g1u[i] * x.w;
        }
      }
    } else {
      const int ko = qq << 5;
      float acc[16];
#pragma unroll
      for (int i = 0; i < 16; ++i) acc[i] = 0.f;
#pragma unroll
      for (int kk = 0; kk < 32; kk += 4) {
        const float wa = W2CR(kk), wb = W2CR(kk + 1), wc = W2CR(kk + 2), wd = W2CR(kk + 3);
#pragma unroll
        for (int i = 0; i < 16; ++i) {
          const float4 z = *(const float4*)&sZ1b[i * 260 + ko + kk];
          acc[i] = fmaf(z.w, wd, fmaf(z.z, wc, fmaf(z.y, wb, fmaf(z.x, wa, acc[i]))));
        }
      }
#pragma unroll
      for (int i = 0; i < 16; ++i) sP[(qq << 10) + (i << 6) + m] = acc[i];
      // w2c slice update (pre-update Z1 from sZ1, g2 from sg2)
      float s2[16];
#pragma unroll
      for (int i = 0; i < 16; ++i) s2[i] = cl * sg2[i * 68 + m];
#pragma unroll
      for (int kk = 0; kk < 32; kk += 4) {
        float d0 = 0.f, d1 = 0.f, d2 = 0.f, d3 = 0.f;
#pragma unroll
        for (int i = 0; i < 16; ++i) {
          const float4 z = *(const float4*)&sZ1[i * 260 + ko + kk];
          d0 = fmaf(s2[i], z.x, d0); d1 = fmaf(s2[i], z.y, d1);
          d2 = fmaf(s2[i], z.z, d2); d3 = fmaf(s2[i], z.w, d3);
        }
        W2CR(kk + 0) -= d0; W2CR(kk + 1) -= d1;
        W2CR(kk + 2) -= d2; W2CR(kk + 3) -= d3;
      }
    }
    __syncthreads();

    // ---- P7: A: Z2b reduce + Attn2 combine + store (2 outputs/thread).
    //      No trailing barrier: B proceeds into next P1 (writes only sA1,
    //      not read here); next writes to sP/sA2p/sg2 are >=2 barriers away.
    if (isA) {
      const int mm = n & 63, iq = (n >> 6) & 3;
#pragma unroll
      for (int r = 0; r < 2; ++r) {
        const int i = iq + 4 * (h2 * 2 + r);
        float v = 0.f;
#pragma unroll
        for (int p = 0; p < 8; ++p) v += sP[(p << 10) + (i << 6) + mm];
        float at = 0.f;
#pragma unroll
        for (int j = 0; j < 16; ++j)
          at = fmaf(sA2p[i * 17 + j] + sA2p[272 + i * 17 + j],
                    sg2[j * 68 + mm], at);
        Out[cb + i * 1024 + mm] = v - sCoBuf[cur * 16 + i] * at;
      }
    }
  }
#undef W1R
#undef W2RR
#undef W2CR
}

// ---------------------------------------------------------------------------
// Workspace (fp32 floats): bXC [0,16.7M) | bXB [16.7M,33.5M) | bZ2b
// [33.5M,50.3M) | bCo [50.3M,+262k).  193 MiB total.  XA (V proj) lives in
// d_out until the final GEMM overwrites it (stream-ordered, safe).
// ---------------------------------------------------------------------------
extern "C" void kernel_launch(void* const* d_in, const int* in_sizes, int n_in,
                              void* d_out, int out_size, void* d_ws, size_t ws_size,
                              hipStream_t stream)
{
  const float* H    = (const float*)d_in[0];
  const float* Wq   = (const float*)d_in[1];
  const float* Wk   = (const float*)d_in[2];
  const float* Wv   = (const float*)d_in[3];
  const float* Wo   = (const float*)d_in[4];
  const float* Wil  = (const float*)d_in[5];
  const float* bil  = (const float*)d_in[6];
  const float* W1   = (const float*)d_in[7];
  const float* W2   = (const float*)d_in[8];
  float* out        = (float*)d_out;

  float* ws    = (float*)d_ws;
  float* bXC   = ws;
  float* bXB   = ws + 16777216;
  float* bZ2b  = ws + 33554432;
  float* bCo   = ws + 50331648;
  float* bXA   = out;

  const int M = Bsz * Lsz, N = Csz, K = Csz;
  dim3 gg(N / 64, M / 64);
  dim3 bb(256);

  gemm64<<<gg, bb, 0, stream>>>(H, Wq, bXC, M, N, K);
  gemm64<<<gg, bb, 0, stream>>>(H, Wk, bXB, M, N, K);
  gemm64<<<gg, bb, 0, stream>>>(H, Wv, bXA, M, N, K);
  ilr_coeff<<<M / 4, 256, 0, stream>>>(H, Wil, bil, bCo);
  ttt_scan<<<Bsz * NHsz, 1024, 0, stream>>>(bXA, bXB, bXC, bCo, W1, W2, bZ2b);
  gemm64<<<gg, bb, 0, stream>>>(bZ2b, Wo, out, M, N, K);
}